// Round 9
// baseline (2329.071 us; speedup 1.0000x reference)
//
#include <hip/hip_runtime.h>

#define H_ 448
#define CIN_ 128
#define HW_ (448*96)   // 43008
#define NT 384

__device__ __forceinline__ float lrelu(float v){ return v > 0.0f ? v : 0.01f*v; }

// Counting sort of 96 pixels by class (NC classes). All threads must call.
template<int NC>
__device__ __forceinline__ void sort_by_class(const unsigned char* s_cls, short* s_perm,
                                              int* s_cnt, int* s_off, int t)
{
    if (t < NC){
        int c = 0;
        for (int p = 0; p < 96; p++) if (s_cls[p] == (unsigned char)t) c++;
        s_cnt[t] = c;
    }
    __syncthreads();
    if (t == 0){
        int a = 0;
        for (int c = 0; c < NC; c++){ s_off[c] = a; a += s_cnt[c]; }
    }
    __syncthreads();
    if (t < NC){
        int o = s_off[t];
        for (int p = 0; p < 96; p++) if (s_cls[p] == (unsigned char)t) s_perm[o++] = (short)p;
    }
    __syncthreads();
}

// Load float4 #k of the virtual expert slab [W0 (1024 f4) | W1 (256 f4) | W2 (128 f4)]
__device__ __forceinline__ float4 slab_ld(const float* W0e, const float* W1e, const float* W2e, int k){
    if (k < 1024) return ((const float4*)W0e)[k];
    if (k < 1280) return ((const float4*)W1e)[k - 1024];
    return ((const float4*)W2e)[k - 1280];
}

__global__ __launch_bounds__(NT, 3)
void cls3_fused(const float* __restrict__ X,
                const float* __restrict__ w1_0, const float* __restrict__ b1_0,
                const float* __restrict__ w1_1, const float* __restrict__ b1_1,
                const float* __restrict__ w1_2, const float* __restrict__ b1_2,
                const float* __restrict__ w2_0, const float* __restrict__ b2_0,
                const float* __restrict__ w2_1, const float* __restrict__ b2_1,
                const float* __restrict__ w2_2, const float* __restrict__ b2_2,
                const float* __restrict__ w3_0, const float* __restrict__ b3_0,
                const float* __restrict__ w3_1, const float* __restrict__ b3_1,
                const float* __restrict__ w3_2, const float* __restrict__ b3_2,
                int* __restrict__ out)
{
    // expert slab layout (floats): W0 [i*32+o] @0 (4096) | W1 [i*32+o] @4096 (1024) | W2 [i*16+o] @5120 (512)
    __shared__ float s_buf[2][5632];          // double-buffered expert slab (45 KB)
    __shared__ unsigned char s_cls[96];       // stage-1 routing
    __shared__ unsigned char s_cls2[96];      // stage-2 routing (clipped inds12)
    __shared__ short s_perm[96];
    __shared__ int   s_raw[96];               // unclipped inds12
    __shared__ int   s_cnt[64];
    __shared__ int   s_off[64];
    __shared__ short s_present[64];
    __shared__ int   s_npres;

    const int h  = blockIdx.x;
    const int t  = threadIdx.x;
    const int g  = t >> 3;          // pixel-group 0..47
    const int j  = t & 7;           // lane within group: owns out-ch {4j..4j+3} (L0/L1), {2j,2j+1} (L2-16), {j} (L2-8)
    const int gb = (t & 63) & ~7;   // group base lane within wave

    // ---------------- Phase A: stage w1 (transposed to [i][o]) + stage-1 compute ----------------
    {
        const float* g0 = w1_0 + (size_t)h*4096;   // [o=32][i=128]
        for (int k = t; k < 4096; k += NT){ const int o = k >> 7, i = k & 127; s_buf[0][i*32 + o] = g0[k]; }
        const float* g1 = w1_1 + (size_t)h*1024;   // [o=32][i=32]
        for (int k = t; k < 1024; k += NT){ const int o = k >> 5, i = k & 31; s_buf[0][4096 + i*32 + o] = g1[k]; }
        const float* g2 = w1_2 + (size_t)h*256;    // [o=8][i=32]
        for (int k = t; k < 256; k += NT){ const int o = k >> 5, i = k & 31; s_buf[0][5120 + i*8 + o] = g2[k]; }
    }
    __syncthreads();
    {
        const float* buf = s_buf[0];
        for (int px = g; px < 96; px += 48){
            const int hw = h*96 + px;
            // L0: 128 -> 32
            float4 acc = *(const float4*)&b1_0[h*32 + 4*j];
            #pragma unroll 8
            for (int i = 0; i < 128; i++){
                const float4 w4 = *(const float4*)&buf[i*32 + 4*j];
                const float xv = X[(size_t)i*HW_ + hw];
                acc.x += xv*w4.x; acc.y += xv*w4.y; acc.z += xv*w4.z; acc.w += xv*w4.w;
            }
            float a0[4] = { lrelu(acc.x), lrelu(acc.y), lrelu(acc.z), lrelu(acc.w) };
            // L1: 32 -> 32 (acts via in-group shfl)
            float4 ac2 = *(const float4*)&b1_1[h*32 + 4*j];
            #pragma unroll
            for (int i = 0; i < 32; i++){
                const float xv = __shfl(a0[i&3], gb + (i>>2), 64);
                const float4 w4 = *(const float4*)&buf[4096 + i*32 + 4*j];
                ac2.x += xv*w4.x; ac2.y += xv*w4.y; ac2.z += xv*w4.z; ac2.w += xv*w4.w;
            }
            float a1[4] = { lrelu(ac2.x), lrelu(ac2.y), lrelu(ac2.z), lrelu(ac2.w) };
            // L2: 32 -> 8 (lane owns channel j)
            float sc = b1_2[h*8 + j];
            #pragma unroll
            for (int i = 0; i < 32; i++){
                const float xv = __shfl(a1[i&3], gb + (i>>2), 64);
                sc += xv * buf[5120 + i*8 + j];
            }
            float best = sc; int bi = j;
            #pragma unroll
            for (int o2 = 1; o2 < 8; o2 <<= 1){
                const float ob = __shfl_xor(best, o2, 64);
                const int  obi = __shfl_xor(bi,  o2, 64);
                if (ob > best || (ob == best && obi < bi)){ best = ob; bi = obi; }
            }
            if (j == 0) s_cls[px] = (unsigned char)bi;
        }
    }
    __syncthreads();

    // ---------------- Phase B: stage 2, expert-major rounds ----------------
    sort_by_class<8>(s_cls, s_perm, s_cnt, s_off, t);
    if (t == 0){
        int n = 0;
        for (int c = 0; c < 8; c++) if (s_cnt[c]) s_present[n++] = (short)c;
        s_npres = n;
    }
    __syncthreads();
    {
        const int R = s_npres;
        {   // prologue: sync-stage present[0] into buf 0
            const long e = (long)h*8 + s_present[0];
            const float* W0e = w2_0 + e*4096; const float* W1e = w2_1 + e*1024; const float* W2e = w2_2 + e*512;
            for (int k = t; k < 1408; k += NT) *(float4*)&s_buf[0][4*k] = slab_ld(W0e, W1e, W2e, k);
        }
        __syncthreads();
        int cur = 0;
        for (int r = 0; r < R; r++){
            const int  c = s_present[r];
            const long e = (long)h*8 + c;
            // issue next expert's loads into registers (T14 async-split)
            float4 p0 = make_float4(0,0,0,0), p1 = p0, p2 = p0, p3 = p0;
            const bool hn = (r + 1 < R);
            if (hn){
                const long e2 = (long)h*8 + s_present[r+1];
                const float* W0n = w2_0 + e2*4096; const float* W1n = w2_1 + e2*1024; const float* W2n = w2_2 + e2*512;
                p0 = slab_ld(W0n, W1n, W2n, t);
                p1 = slab_ld(W0n, W1n, W2n, t + 384);
                p2 = slab_ld(W0n, W1n, W2n, t + 768);
                if (t < 256) p3 = slab_ld(W0n, W1n, W2n, t + 1152);
            }
            // compute this expert's pixels from LDS
            const float* buf = s_buf[cur];
            const int off = s_off[c], end = off + s_cnt[c];
            const float* bp0 = b2_0 + e*32; const float* bp1 = b2_1 + e*32; const float* bp2 = b2_2 + e*16;
            for (int pos = off + g; pos < end; pos += 48){
                const int px = s_perm[pos];
                const int hw = h*96 + px;
                float4 acc = *(const float4*)&bp0[4*j];
                #pragma unroll 8
                for (int i = 0; i < 128; i++){
                    const float4 w4 = *(const float4*)&buf[i*32 + 4*j];
                    const float xv = X[(size_t)i*HW_ + hw];
                    acc.x += xv*w4.x; acc.y += xv*w4.y; acc.z += xv*w4.z; acc.w += xv*w4.w;
                }
                float a0[4] = { lrelu(acc.x), lrelu(acc.y), lrelu(acc.z), lrelu(acc.w) };
                float4 ac2 = *(const float4*)&bp1[4*j];
                #pragma unroll
                for (int i = 0; i < 32; i++){
                    const float xv = __shfl(a0[i&3], gb + (i>>2), 64);
                    const float4 w4 = *(const float4*)&buf[4096 + i*32 + 4*j];
                    ac2.x += xv*w4.x; ac2.y += xv*w4.y; ac2.z += xv*w4.z; ac2.w += xv*w4.w;
                }
                float a1[4] = { lrelu(ac2.x), lrelu(ac2.y), lrelu(ac2.z), lrelu(ac2.w) };
                float2 sc2 = *(const float2*)&bp2[2*j];
                #pragma unroll
                for (int i = 0; i < 32; i++){
                    const float xv = __shfl(a1[i&3], gb + (i>>2), 64);
                    const float2 w2v = *(const float2*)&buf[5120 + i*16 + 2*j];
                    sc2.x += xv*w2v.x; sc2.y += xv*w2v.y;
                }
                float best = sc2.x; int bi = 2*j;
                if (sc2.y > best){ best = sc2.y; bi = 2*j + 1; }
                #pragma unroll
                for (int o2 = 1; o2 < 8; o2 <<= 1){
                    const float ob = __shfl_xor(best, o2, 64);
                    const int  obi = __shfl_xor(bi,  o2, 64);
                    if (ob > best || (ob == best && obi < bi)){ best = ob; bi = obi; }
                }
                if (j == 0){
                    const int raw = c*8 + bi - 4;
                    s_raw[px]  = raw;
                    s_cls2[px] = (unsigned char)(raw < 0 ? 0 : (raw > 63 ? 63 : raw));
                }
            }
            // land the prefetch into the other buffer
            if (hn){
                float* nb = s_buf[cur ^ 1];
                *(float4*)&nb[4*t]        = p0;
                *(float4*)&nb[4*(t+384)]  = p1;
                *(float4*)&nb[4*(t+768)]  = p2;
                if (t < 256) *(float4*)&nb[4*(t+1152)] = p3;
            }
            __syncthreads();
            if (hn) cur ^= 1;
        }
    }

    // ---------------- Phase C: stage 3, expert-major rounds ----------------
    sort_by_class<64>(s_cls2, s_perm, s_cnt, s_off, t);
    if (t == 0){
        int n = 0;
        for (int c = 0; c < 64; c++) if (s_cnt[c]) s_present[n++] = (short)c;
        s_npres = n;
    }
    __syncthreads();
    {
        const int R = s_npres;
        {   // prologue: sync-stage present[0] into buf 0
            const long e = (long)h*64 + s_present[0];
            const float* W0e = w3_0 + e*4096; const float* W1e = w3_1 + e*1024; const float* W2e = w3_2 + e*512;
            for (int k = t; k < 1408; k += NT) *(float4*)&s_buf[0][4*k] = slab_ld(W0e, W1e, W2e, k);
        }
        __syncthreads();
        int cur = 0;
        for (int r = 0; r < R; r++){
            const int  c = s_present[r];
            const long e = (long)h*64 + c;
            float4 p0 = make_float4(0,0,0,0), p1 = p0, p2 = p0, p3 = p0;
            const bool hn = (r + 1 < R);
            if (hn){
                const long e2 = (long)h*64 + s_present[r+1];
                const float* W0n = w3_0 + e2*4096; const float* W1n = w3_1 + e2*1024; const float* W2n = w3_2 + e2*512;
                p0 = slab_ld(W0n, W1n, W2n, t);
                p1 = slab_ld(W0n, W1n, W2n, t + 384);
                p2 = slab_ld(W0n, W1n, W2n, t + 768);
                if (t < 256) p3 = slab_ld(W0n, W1n, W2n, t + 1152);
            }
            const float* buf = s_buf[cur];
            const int off = s_off[c], end = off + s_cnt[c];
            const float* bp0 = b3_0 + e*32; const float* bp1 = b3_1 + e*32; const float* bp2 = b3_2 + e*16;
            for (int pos = off + g; pos < end; pos += 48){
                const int px = s_perm[pos];
                const int hw = h*96 + px;
                float4 acc = *(const float4*)&bp0[4*j];
                #pragma unroll 8
                for (int i = 0; i < 128; i++){
                    const float4 w4 = *(const float4*)&buf[i*32 + 4*j];
                    const float xv = X[(size_t)i*HW_ + hw];
                    acc.x += xv*w4.x; acc.y += xv*w4.y; acc.z += xv*w4.z; acc.w += xv*w4.w;
                }
                float a0[4] = { lrelu(acc.x), lrelu(acc.y), lrelu(acc.z), lrelu(acc.w) };
                float4 ac2 = *(const float4*)&bp1[4*j];
                #pragma unroll
                for (int i = 0; i < 32; i++){
                    const float xv = __shfl(a0[i&3], gb + (i>>2), 64);
                    const float4 w4 = *(const float4*)&buf[4096 + i*32 + 4*j];
                    ac2.x += xv*w4.x; ac2.y += xv*w4.y; ac2.z += xv*w4.z; ac2.w += xv*w4.w;
                }
                float a1[4] = { lrelu(ac2.x), lrelu(ac2.y), lrelu(ac2.z), lrelu(ac2.w) };
                float2 sc2 = *(const float2*)&bp2[2*j];
                #pragma unroll
                for (int i = 0; i < 32; i++){
                    const float xv = __shfl(a1[i&3], gb + (i>>2), 64);
                    const float2 w2v = *(const float2*)&buf[5120 + i*16 + 2*j];
                    sc2.x += xv*w2v.x; sc2.y += xv*w2v.y;
                }
                float best = sc2.x; int bi = 2*j;
                if (sc2.y > best){ best = sc2.y; bi = 2*j + 1; }
                #pragma unroll
                for (int o2 = 1; o2 < 8; o2 <<= 1){
                    const float ob = __shfl_xor(best, o2, 64);
                    const int  obi = __shfl_xor(bi,  o2, 64);
                    if (ob > best || (ob == best && obi < bi)){ best = ob; bi = obi; }
                }
                if (j == 0){
                    int v = s_raw[px]*8 + bi - 4;
                    v = v < 0 ? 0 : (v > 511 ? 511 : v);
                    out[h*96 + px] = v;
                }
            }
            if (hn){
                float* nb = s_buf[cur ^ 1];
                *(float4*)&nb[4*t]        = p0;
                *(float4*)&nb[4*(t+384)]  = p1;
                *(float4*)&nb[4*(t+768)]  = p2;
                if (t < 256) *(float4*)&nb[4*(t+1152)] = p3;
            }
            __syncthreads();
            if (hn) cur ^= 1;
        }
    }
}

extern "C" void kernel_launch(void* const* d_in, const int* in_sizes, int n_in,
                              void* d_out, int out_size, void* d_ws, size_t ws_size,
                              hipStream_t stream) {
    const float* X    = (const float*)d_in[0];
    const float* w1_0 = (const float*)d_in[1];
    const float* b1_0 = (const float*)d_in[2];
    const float* w1_1 = (const float*)d_in[3];
    const float* b1_1 = (const float*)d_in[4];
    const float* w1_2 = (const float*)d_in[5];
    const float* b1_2 = (const float*)d_in[6];
    const float* w2_0 = (const float*)d_in[7];
    const float* b2_0 = (const float*)d_in[8];
    const float* w2_1 = (const float*)d_in[9];
    const float* b2_1 = (const float*)d_in[10];
    const float* w2_2 = (const float*)d_in[11];
    const float* b2_2 = (const float*)d_in[12];
    const float* w3_0 = (const float*)d_in[13];
    const float* b3_0 = (const float*)d_in[14];
    const float* w3_1 = (const float*)d_in[15];
    const float* b3_1 = (const float*)d_in[16];
    const float* w3_2 = (const float*)d_in[17];
    const float* b3_2 = (const float*)d_in[18];
    int* out = (int*)d_out;

    cls3_fused<<<H_, NT, 0, stream>>>(X,
        w1_0, b1_0, w1_1, b1_1, w1_2, b1_2,
        w2_0, b2_0, w2_1, b2_1, w2_2, b2_2,
        w3_0, b3_0, w3_1, b3_1, w3_2, b3_2,
        out);
}

// Round 10
// 155.439 us; speedup vs baseline: 14.9839x; 14.9839x over previous
//
#include <hip/hip_runtime.h>

#define H_ 448
#define CIN_ 128
#define HW_ (448*96)   // 43008
#define PPB 48

__device__ __forceinline__ float lrelu(float v){ return v > 0.0f ? v : 0.01f*v; }

// XCD-pairing block decode: the two half-line blocks of line h land on the same XCD
// (assuming dispatch round-robins XCDs by blockIdx % 8).
__device__ __forceinline__ void decode_block(int d, int& h, int& wb){
    const int r = d & 15, q = d >> 4;
    h  = (r & 7) + (q << 3);
    wb = (r >> 3) * PPB;
}

// Counting sort of PPB pixels by class (NC classes). All threads must call.
template<int NC>
__device__ __forceinline__ void sort_by_class(const unsigned char* s_cls, short* s_perm,
                                              int* s_cnt, int* s_off, int t)
{
    if (t < NC){
        int c = 0;
        for (int p = 0; p < PPB; p++) if (s_cls[p] == (unsigned char)t) c++;
        s_cnt[t] = c;
    }
    __syncthreads();
    if (t == 0){
        int a = 0;
        for (int c = 0; c < NC; c++){ s_off[c] = a; a += s_cnt[c]; }
    }
    __syncthreads();
    if (t < NC){
        int o = s_off[t];
        for (int p = 0; p < PPB; p++) if (s_cls[p] == (unsigned char)t) s_perm[o++] = (short)p;
    }
    __syncthreads();
}

// ================= K1: stage 1 (half-line blocks) =================
__global__ __launch_bounds__(384, 4)
void k1_stage1(const float* __restrict__ X,
               const float* __restrict__ w1_0, const float* __restrict__ b1_0,
               const float* __restrict__ w1_1, const float* __restrict__ b1_1,
               const float* __restrict__ w1_2, const float* __restrict__ b1_2,
               unsigned char* __restrict__ inds1)
{
    __shared__ float s_w0[4096];
    __shared__ float s_w1[1024];
    __shared__ float s_w2[256];
    __shared__ float s_A[PPB*33];
    __shared__ float s_B[PPB*33];

    int h, wb; decode_block(blockIdx.x, h, wb);
    const int t  = threadIdx.x;
    const int w  = t % PPB;
    const int s  = t / PPB;          // 0..7 owns 4 channels
    const int hw = h*96 + wb + w;

    const float* g0 = w1_0 + (size_t)h*4096;
    for (int j = t; j < 4096; j += 384) s_w0[j] = g0[j];
    const float* g1 = w1_1 + (size_t)h*1024;
    for (int j = t; j < 1024; j += 384) s_w1[j] = g1[j];
    const float* g2 = w1_2 + (size_t)h*256;
    for (int j = t; j < 256; j += 384) s_w2[j] = g2[j];
    __syncthreads();

    // L0: 128 -> 32
    {
        float acc[4];
        const float* bp = b1_0 + h*32 + s*4;
        #pragma unroll
        for (int k=0;k<4;k++) acc[k] = bp[k];
        #pragma unroll 4
        for (int i4=0;i4<32;i4++){
            const float x0 = X[(size_t)(4*i4+0)*HW_ + hw];
            const float x1 = X[(size_t)(4*i4+1)*HW_ + hw];
            const float x2 = X[(size_t)(4*i4+2)*HW_ + hw];
            const float x3 = X[(size_t)(4*i4+3)*HW_ + hw];
            #pragma unroll
            for (int k=0;k<4;k++){
                const float4 q = *(const float4*)&s_w0[(s*4+k)*128 + 4*i4];
                acc[k] += x0*q.x; acc[k] += x1*q.y; acc[k] += x2*q.z; acc[k] += x3*q.w;
            }
        }
        #pragma unroll
        for (int k=0;k<4;k++) s_A[w*33 + s*4 + k] = lrelu(acc[k]);
    }
    __syncthreads();

    // L1: 32 -> 32
    {
        float acc[4];
        const float* bp = b1_1 + h*32 + s*4;
        #pragma unroll
        for (int k=0;k<4;k++) acc[k] = bp[k];
        #pragma unroll
        for (int i4=0;i4<8;i4++){
            const float x0 = s_A[w*33 + 4*i4+0];
            const float x1 = s_A[w*33 + 4*i4+1];
            const float x2 = s_A[w*33 + 4*i4+2];
            const float x3 = s_A[w*33 + 4*i4+3];
            #pragma unroll
            for (int k=0;k<4;k++){
                const float4 q = *(const float4*)&s_w1[(s*4+k)*32 + 4*i4];
                acc[k] += x0*q.x; acc[k] += x1*q.y; acc[k] += x2*q.z; acc[k] += x3*q.w;
            }
        }
        #pragma unroll
        for (int k=0;k<4;k++) s_B[w*33 + s*4 + k] = lrelu(acc[k]);
    }
    __syncthreads();

    // L2: 32 -> 8 (each s owns 1 output)
    {
        float acc = b1_2[h*8 + s];
        #pragma unroll
        for (int i4=0;i4<8;i4++){
            const float4 q = *(const float4*)&s_w2[s*32 + 4*i4];
            acc += s_B[w*33 + 4*i4+0]*q.x;
            acc += s_B[w*33 + 4*i4+1]*q.y;
            acc += s_B[w*33 + 4*i4+2]*q.z;
            acc += s_B[w*33 + 4*i4+3]*q.w;
        }
        s_A[w*33 + s] = acc;
    }
    __syncthreads();

    if (s == 0){
        const float* sc = &s_A[w*33];
        float best = sc[0]; int bi = 0;
        #pragma unroll
        for (int k=1;k<8;k++){ const float v = sc[k]; if (v > best){ best = v; bi = k; } }
        inds1[hw] = (unsigned char)bi;
    }
}

// ================= K2: stage 2 (half-line blocks, sorted demand-gather) =================
__global__ __launch_bounds__(384, 4)
void k2_stage2(const float* __restrict__ X,
               const float* __restrict__ w0, const float* __restrict__ b0,
               const float* __restrict__ w1, const float* __restrict__ b1,
               const float* __restrict__ w2, const float* __restrict__ b2,
               const unsigned char* __restrict__ inds1,
               signed char* __restrict__ raw12, unsigned char* __restrict__ cls2)
{
    __shared__ float s_A[PPB*36];
    __shared__ float s_B[PPB*36];
    __shared__ unsigned char s_cls[PPB];
    __shared__ short s_perm[PPB];
    __shared__ int   s_cnt[8];
    __shared__ int   s_off[8];

    int h, wb; decode_block(blockIdx.x, h, wb);
    const int t = threadIdx.x;
    if (t < PPB) s_cls[t] = inds1[h*96 + wb + t];
    __syncthreads();
    sort_by_class<8>(s_cls, s_perm, s_cnt, s_off, t);

    const int p = t >> 3;   // sorted pixel slot 0..47
    const int j = t & 7;    // owns 4 channels
    const int sp = s_perm[p];
    const int c  = s_cls[sp];
    const long e = (long)h*8 + c;
    const int hw = h*96 + wb + sp;
    const float* W0 = w0 + e*4096 + j*4;
    const float* W1 = w1 + e*1024 + j*4;
    const float* W2 = w2 + e*512  + j*2;

    // L0: 128 -> 32
    float4 acc = *(const float4*)&b0[e*32 + j*4];
    #pragma unroll 8
    for (int i=0;i<128;i++){
        const float xv = X[(size_t)i*HW_ + hw];
        const float4 q = *(const float4*)&W0[i*32];
        acc.x += xv*q.x; acc.y += xv*q.y; acc.z += xv*q.z; acc.w += xv*q.w;
    }
    *(float4*)&s_A[p*36 + j*4] = make_float4(lrelu(acc.x),lrelu(acc.y),lrelu(acc.z),lrelu(acc.w));
    __syncthreads();

    // L1: 32 -> 32
    float4 ac2 = *(const float4*)&b1[e*32 + j*4];
    #pragma unroll 8
    for (int i=0;i<32;i++){
        const float xv = s_A[p*36 + i];
        const float4 q = *(const float4*)&W1[i*32];
        ac2.x += xv*q.x; ac2.y += xv*q.y; ac2.z += xv*q.z; ac2.w += xv*q.w;
    }
    *(float4*)&s_B[p*36 + j*4] = make_float4(lrelu(ac2.x),lrelu(ac2.y),lrelu(ac2.z),lrelu(ac2.w));
    __syncthreads();

    // L2: 32 -> 16
    float2 sc = *(const float2*)&b2[e*16 + j*2];
    #pragma unroll 8
    for (int i=0;i<32;i++){
        const float xv = s_B[p*36 + i];
        const float2 r = *(const float2*)&W2[i*16];
        sc.x += xv*r.x; sc.y += xv*r.y;
    }
    float best = sc.x; int bi = j*2;
    if (sc.y > best){ best = sc.y; bi = j*2+1; }
    #pragma unroll
    for (int off=1; off<8; off<<=1){
        const float ob = __shfl_xor(best, off, 64);
        const int  obi = __shfl_xor(bi,  off, 64);
        if (ob > best || (ob == best && obi < bi)){ best = ob; bi = obi; }
    }
    if (j == 0){
        const int raw = c*8 + bi - 4;
        raw12[hw] = (signed char)raw;
        cls2[hw]  = (unsigned char)(raw < 0 ? 0 : (raw > 63 ? 63 : raw));
    }
}

// ================= K3: stage 3 =================
__global__ __launch_bounds__(384, 4)
void k3_stage3(const float* __restrict__ X,
               const float* __restrict__ w0, const float* __restrict__ b0,
               const float* __restrict__ w1, const float* __restrict__ b1,
               const float* __restrict__ w2, const float* __restrict__ b2,
               const unsigned char* __restrict__ cls2,
               const signed char* __restrict__ raw12,
               int* __restrict__ out)
{
    __shared__ float s_A[PPB*36];
    __shared__ float s_B[PPB*36];
    __shared__ unsigned char s_cls[PPB];
    __shared__ short s_perm[PPB];
    __shared__ int   s_cnt[64];
    __shared__ int   s_off[64];

    int h, wb; decode_block(blockIdx.x, h, wb);
    const int t = threadIdx.x;
    if (t < PPB) s_cls[t] = cls2[h*96 + wb + t];
    __syncthreads();
    sort_by_class<64>(s_cls, s_perm, s_cnt, s_off, t);

    const int p = t >> 3;
    const int j = t & 7;
    const int sp = s_perm[p];
    const int c  = s_cls[sp];
    const long e = (long)h*64 + c;
    const int hw = h*96 + wb + sp;
    const float* W0 = w0 + e*4096 + j*4;
    const float* W1 = w1 + e*1024 + j*4;
    const float* W2 = w2 + e*512  + j*2;

    float4 acc = *(const float4*)&b0[e*32 + j*4];
    #pragma unroll 8
    for (int i=0;i<128;i++){
        const float xv = X[(size_t)i*HW_ + hw];
        const float4 q = *(const float4*)&W0[i*32];
        acc.x += xv*q.x; acc.y += xv*q.y; acc.z += xv*q.z; acc.w += xv*q.w;
    }
    *(float4*)&s_A[p*36 + j*4] = make_float4(lrelu(acc.x),lrelu(acc.y),lrelu(acc.z),lrelu(acc.w));
    __syncthreads();

    float4 ac2 = *(const float4*)&b1[e*32 + j*4];
    #pragma unroll 8
    for (int i=0;i<32;i++){
        const float xv = s_A[p*36 + i];
        const float4 q = *(const float4*)&W1[i*32];
        ac2.x += xv*q.x; ac2.y += xv*q.y; ac2.z += xv*q.z; ac2.w += xv*q.w;
    }
    *(float4*)&s_B[p*36 + j*4] = make_float4(lrelu(ac2.x),lrelu(ac2.y),lrelu(ac2.z),lrelu(ac2.w));
    __syncthreads();

    float2 sc = *(const float2*)&b2[e*16 + j*2];
    #pragma unroll 8
    for (int i=0;i<32;i++){
        const float xv = s_B[p*36 + i];
        const float2 r = *(const float2*)&W2[i*16];
        sc.x += xv*r.x; sc.y += xv*r.y;
    }
    float best = sc.x; int bi = j*2;
    if (sc.y > best){ best = sc.y; bi = j*2+1; }
    #pragma unroll
    for (int off=1; off<8; off<<=1){
        const float ob = __shfl_xor(best, off, 64);
        const int  obi = __shfl_xor(bi,  off, 64);
        if (ob > best || (ob == best && obi < bi)){ best = ob; bi = obi; }
    }
    if (j == 0){
        int v = (int)raw12[hw]*8 + bi - 4;
        v = v < 0 ? 0 : (v > 511 ? 511 : v);
        out[hw] = v;
    }
}

extern "C" void kernel_launch(void* const* d_in, const int* in_sizes, int n_in,
                              void* d_out, int out_size, void* d_ws, size_t ws_size,
                              hipStream_t stream) {
    const float* X    = (const float*)d_in[0];
    const float* w1_0 = (const float*)d_in[1];
    const float* b1_0 = (const float*)d_in[2];
    const float* w1_1 = (const float*)d_in[3];
    const float* b1_1 = (const float*)d_in[4];
    const float* w1_2 = (const float*)d_in[5];
    const float* b1_2 = (const float*)d_in[6];
    const float* w2_0 = (const float*)d_in[7];
    const float* b2_0 = (const float*)d_in[8];
    const float* w2_1 = (const float*)d_in[9];
    const float* b2_1 = (const float*)d_in[10];
    const float* w2_2 = (const float*)d_in[11];
    const float* b2_2 = (const float*)d_in[12];
    const float* w3_0 = (const float*)d_in[13];
    const float* b3_0 = (const float*)d_in[14];
    const float* w3_1 = (const float*)d_in[15];
    const float* b3_1 = (const float*)d_in[16];
    const float* w3_2 = (const float*)d_in[17];
    const float* b3_2 = (const float*)d_in[18];
    int* out = (int*)d_out;

    unsigned char* inds1 = (unsigned char*)d_ws;
    unsigned char* cls2  = inds1 + HW_;
    signed char*   raw12 = (signed char*)(cls2 + HW_);

    k1_stage1<<<H_*2, 384, 0, stream>>>(X, w1_0, b1_0, w1_1, b1_1, w1_2, b1_2, inds1);
    k2_stage2<<<H_*2, 384, 0, stream>>>(X, w2_0, b2_0, w2_1, b2_1, w2_2, b2_2, inds1, raw12, cls2);
    k3_stage3<<<H_*2, 384, 0, stream>>>(X, w3_0, b3_0, w3_1, b3_1, w3_2, b3_2, cls2, raw12, out);
}